// Round 2
// baseline (485.684 us; speedup 1.0000x reference)
//
#include <hip/hip_runtime.h>

// RouterModel: top-1-of-2 softmax router with dense dispatch.
//   score = softmax(x @ W)          [N,2]
//   path  = argmax(score)           (tie -> 0, numpy first-occurrence)
//   x0 = x * (path==0 ? p0 : 0); x1 = x * (path==1 ? p1 : 0); xc = x0 + x1
//
// Two-pass structure: pass 1 computes per-token gates (read-only stream,
// reduction latency off the store path); pass 2 is a pure elementwise
// dispatch stream (no cross-lane ops, block-uniform gate via scalar load,
// nontemporal stores so the 403 MB output stream doesn't evict x from L3
// between pass 1 and pass 2).
// Traffic: pass1 reads 134 MB; pass2 reads 134 MB (likely L3-hit) + writes
// 403 MB. Floor ~110 us combined at 6.3 TB/s, less if L3 absorbs re-read.

constexpr int kN = 32768;
constexpr int kD = 1024;
constexpr long long kND = (long long)kN * kD;

// clang-native 4-float vector: __builtin_nontemporal_store requires a native
// vector type, HIP's float4 (HIP_vector_type class) is rejected.
typedef float f32x4 __attribute__((ext_vector_type(4)));

// ---------------------------------------------------------------------------
// Pass 1: one wave (64 lanes) per token. Lane l holds float4 indices
// {l, l+64, l+128, l+192} of the 256-float4 row: coalesced 16B/lane loads.
// Butterfly-reduce the two dot products, softmax+argmax, lane 0 writes the
// gate pair {g0, g1} (gc = g0+g1 recomputed in pass 2).
__global__ __launch_bounds__(256) void router_score(
    const float* __restrict__ x, const float* __restrict__ W,
    float2* __restrict__ gates)
{
    const int wave_in_blk = threadIdx.x >> 6;
    const int lane        = threadIdx.x & 63;
    const int t           = blockIdx.x * 4 + wave_in_blk;   // token id

    const float4* __restrict__ row4 = (const float4*)(x + (long long)t * kD);
    const float4* __restrict__ W4   = (const float4*)W;     // interleaved [D,2]

    float s0 = 0.f, s1 = 0.f;
#pragma unroll
    for (int j = 0; j < 4; ++j) {
        const int idx = lane + j * 64;          // float4 index within row
        const float4 v  = row4[idx];
        const float4 wa = W4[2 * idx];          // {W0[d],W1[d],W0[d+1],W1[d+1]}
        const float4 wb = W4[2 * idx + 1];      // {W0[d+2],W1[d+2],W0[d+3],W1[d+3]}
        s0 += v.x * wa.x + v.y * wa.z + v.z * wb.x + v.w * wb.z;
        s1 += v.x * wa.y + v.y * wa.w + v.z * wb.y + v.w * wb.w;
    }

    // 64-lane butterfly reduction (wave = 64 on CDNA)
#pragma unroll
    for (int off = 32; off >= 1; off >>= 1) {
        s0 += __shfl_xor(s0, off, 64);
        s1 += __shfl_xor(s1, off, 64);
    }

    if (lane == 0) {
        // 2-way softmax (exact fp32) + first-occurrence argmax
        const float m   = fmaxf(s0, s1);
        const float e0  = expf(s0 - m);
        const float e1  = expf(s1 - m);
        const float inv = 1.f / (e0 + e1);
        const float p0  = e0 * inv;
        const float p1  = e1 * inv;
        const int path  = (s1 > s0) ? 1 : 0;    // tie -> 0, matches jnp.argmax
        gates[t] = make_float2(path == 0 ? p0 : 0.f,
                               path == 1 ? p1 : 0.f);
    }
}

// ---------------------------------------------------------------------------
// Pass 2: pure streaming dispatch. Block of 256 threads covers 4 tokens
// (1024 float4s, contiguous). For fixed j the token index is thread-uniform
// (blockIdx.x*4 + j) -> gates load compiles to a scalar load (constant
// cache), zero VGPR/VMEM cost per lane. 1 float4 load + 3 NT float4 stores
// per element; no cross-lane dependencies anywhere.
__global__ __launch_bounds__(256) void router_dispatch(
    const float* __restrict__ x, const float2* __restrict__ gates,
    float* __restrict__ out)
{
    const long long base = (long long)blockIdx.x * 1024 + threadIdx.x; // float4 units
    const f32x4* __restrict__ x4 = (const f32x4*)x;
    f32x4* __restrict__ o0 = (f32x4*)out;
    f32x4* __restrict__ o1 = (f32x4*)(out + kND);
    f32x4* __restrict__ oc = (f32x4*)(out + 2 * kND);

    // Issue all 4 row loads up front (4 x 16B in flight per thread).
    f32x4 v[4];
#pragma unroll
    for (int j = 0; j < 4; ++j) v[j] = x4[base + j * 256];

    const int t0 = blockIdx.x * 4;
#pragma unroll
    for (int j = 0; j < 4; ++j) {
        const float2 g  = gates[t0 + j];        // uniform -> s_load
        const float g0  = g.x;
        const float g1  = g.y;
        const float gc  = g0 + g1;              // == max(p0,p1)
        const long long i = base + j * 256;
        const f32x4 a = v[j];
        __builtin_nontemporal_store(a * g0, &o0[i]);
        __builtin_nontemporal_store(a * g1, &o1[i]);
        __builtin_nontemporal_store(a * gc, &oc[i]);
    }
}

extern "C" void kernel_launch(void* const* d_in, const int* in_sizes, int n_in,
                              void* d_out, int out_size, void* d_ws, size_t ws_size,
                              hipStream_t stream)
{
    const float* x = (const float*)d_in[0];   // [N, D] fp32
    const float* W = (const float*)d_in[1];   // [D, 2] fp32
    float* out     = (float*)d_out;           // x0 | x1 | xc, each [N, D]
    float2* gates  = (float2*)d_ws;           // [N] gate pairs, 256 KB

    const int blocks = kN / 4;                // 8192
    router_score<<<blocks, 256, 0, stream>>>(x, W, gates);
    router_dispatch<<<blocks, 256, 0, stream>>>(x, gates, out);
}